// Round 10
// baseline (293.913 us; speedup 1.0000x reference)
//
#include <hip/hip_runtime.h>
#include <hip/hip_bf16.h>
#include <stdint.h>

typedef unsigned short u16;
typedef __bf16 bf16x8 __attribute__((ext_vector_type(8)));
typedef float f32x4 __attribute__((ext_vector_type(4)));
typedef u16 ushort8 __attribute__((ext_vector_type(8)));
typedef short short4v __attribute__((ext_vector_type(4)));

__device__ __forceinline__ u16 f2bf(float f) {
    unsigned int u = __builtin_bit_cast(unsigned int, f);
    u += 0x7fffu + ((u >> 16) & 1u);
    return (u16)(u >> 16);
}

// 2x f32 -> packed bf16 (RNE) via the HIP intrinsic (proven round 7).
__device__ __forceinline__ unsigned pk2(float a, float b) {
    __hip_bfloat162 h = __float22bfloat162_rn(float2{a, b});
    unsigned u;
    __builtin_memcpy(&u, &h, 4);
    return u;
}

#define MFMA16(a, b, c) __builtin_amdgcn_mfma_f32_16x16x32_bf16( \
    __builtin_bit_cast(bf16x8, a), __builtin_bit_cast(bf16x8, b), c, 0, 0, 0)

#if defined(__has_builtin)
#if __has_builtin(__builtin_amdgcn_exp2f)
#define EXP2(x) __builtin_amdgcn_exp2f(x)
#endif
#endif
#ifndef EXP2
#define EXP2(x) __expf((x) * 0.69314718f)
#endif

// async global->LDS, 16B per lane. LDS dest = wave-uniform base + lane*16.
__device__ __forceinline__ void async16(void* lds, const void* g) {
    __builtin_amdgcn_global_load_lds(
        (const __attribute__((address_space(1))) unsigned int*)(uintptr_t)g,
        (__attribute__((address_space(3))) unsigned int*)(unsigned int)(uintptr_t)lds,
        16, 0, 0);
}

// ---------------------------------------------------------------------------
// convert fp32 -> bf16, 8 elems/thread
// ---------------------------------------------------------------------------
__global__ __launch_bounds__(256) void convert_bf16(
    const float* __restrict__ src, u16* __restrict__ dst)
{
    int i = blockIdx.x * 256 + threadIdx.x;
    float4 f0 = ((const float4*)src)[i * 2];
    float4 f1 = ((const float4*)src)[i * 2 + 1];
    ushort8 v;
    v[0]=f2bf(f0.x); v[1]=f2bf(f0.y); v[2]=f2bf(f0.z); v[3]=f2bf(f0.w);
    v[4]=f2bf(f1.x); v[5]=f2bf(f1.y); v[6]=f2bf(f1.z); v[7]=f2bf(f1.w);
    ((ushort8*)dst)[i] = v;
}

// ---------------------------------------------------------------------------
// transpose+convert: src fp32 [K][N] -> dst bf16 [N][K]; 64x64 tiles
// ---------------------------------------------------------------------------
__global__ __launch_bounds__(256) void transpose_convert(
    const float* __restrict__ src, u16* __restrict__ dst, int N, int K)
{
    __shared__ u16 T[64][68];
    const int k0 = blockIdx.x * 64, n0 = blockIdx.y * 64;
    const int tid = threadIdx.x;
    const int rr = tid >> 4, cc = (tid & 15) * 4;
    #pragma unroll
    for (int rnd = 0; rnd < 4; ++rnd) {
        int r = rr + rnd * 16;
        float4 f = *(const float4*)&src[(size_t)(k0 + r) * N + n0 + cc];
        u16 v[4] = {f2bf(f.x), f2bf(f.y), f2bf(f.z), f2bf(f.w)};
        *(unsigned long long*)&T[r][cc] = *(unsigned long long*)v;
    }
    __syncthreads();
    #pragma unroll
    for (int rnd = 0; rnd < 4; ++rnd) {
        int rn = rr + rnd * 16;
        u16 v[4];
        #pragma unroll
        for (int j = 0; j < 4; ++j) v[j] = T[cc + j][rn];
        *(unsigned long long*)&dst[(size_t)(n0 + rn) * K + k0 + cc] =
            *(unsigned long long*)v;
    }
}

// ===========================================================================
// qkv mainloop: 256x256 / BK=32, 512 threads = 8 waves (2M x 4N).
// 2 x 32KB LDS -> 2 blocks/CU. (round-4 version, best so far: 85us)
// ===========================================================================
#define NT32 32      // K=1024 / BK=32
#define BUF32 16384  // u16 per buffer: A 8192 (256x32) + B 8192 (256x32)

__device__ __forceinline__ void stage32(
    const u16* __restrict__ A, const u16* __restrict__ Bt,
    u16* Lb, int m0, int n0, int k0, int w, int lane)
{
    const int rbl = lane >> 5;          // which rb of the wave's pair
    const int chunk = (lane >> 3) & 3;  // k-chunk of 8 u16
    const int row = lane & 7;
    #pragma unroll
    for (int r = 0; r < 2; ++r) {
        int rb = w * 4 + r * 2 + rbl;
        async16(Lb + (w * 4 + r * 2) * 256,
                A + (size_t)(m0 + rb * 8 + row) * 1024 + k0 + chunk * 8);
    }
    #pragma unroll
    for (int r = 0; r < 2; ++r) {
        int rb = w * 4 + r * 2 + rbl;
        async16(Lb + 8192 + (w * 4 + r * 2) * 256,
                Bt + (size_t)(n0 + rb * 8 + row) * 1024 + k0 + chunk * 8);
    }
}

__device__ __forceinline__ void gemm_mainloop32(
    const u16* __restrict__ A, const u16* __restrict__ Bt,
    u16* L, int m0, int n0, int tid, f32x4 acc[8][4])
{
    const int lane = tid & 63, w = tid >> 6;
    const int lr = lane & 15, quad = lane >> 4;
    const int wm = w >> 2, wn = w & 3;
    const int arb = wm * 16 + (lr >> 3);   // + mt*2
    const int brb = wn * 8 + (lr >> 3);    // + nt*2
    const int foff = quad * 64 + (lr & 7) * 8;

    // prologue: stage T0, drain, barrier
    stage32(A, Bt, L, m0, n0, 0, w, lane);
    asm volatile("s_waitcnt vmcnt(0)" ::: "memory");
    __builtin_amdgcn_s_barrier();
    asm volatile("" ::: "memory");

    #pragma unroll 2
    for (int t = 0; t < NT32; ++t) {
        const u16* As = L + (t & 1) * BUF32;
        const u16* Bs = As + 8192;

        // stage next tile; counted wait: tile t landed, t+1 stays in flight
        if (t + 1 < NT32) {
            stage32(A, Bt, L + ((t + 1) & 1) * BUF32, m0, n0, (t + 1) * 32,
                    w, lane);
            asm volatile("s_waitcnt vmcnt(4)" ::: "memory");
        } else {
            asm volatile("s_waitcnt vmcnt(0)" ::: "memory");
        }
        __builtin_amdgcn_s_barrier();   // open: buf[t&1] visible to all waves
        asm volatile("" ::: "memory");

        ushort8 b[4], a03[4], a47[4];
        #pragma unroll
        for (int nt = 0; nt < 4; ++nt)
            b[nt] = *(const ushort8*)&Bs[(brb + nt * 2) * 256 + foff];
        #pragma unroll
        for (int mt = 0; mt < 4; ++mt)
            a03[mt] = *(const ushort8*)&As[(arb + mt * 2) * 256 + foff];
        __builtin_amdgcn_sched_barrier(0);   // pin issue order: b+a03 first
        #pragma unroll
        for (int mt = 0; mt < 4; ++mt)
            a47[mt] = *(const ushort8*)&As[(arb + (mt + 4) * 2) * 256 + foff];
        // counted lgkm: 12 issued, wait to <=4 -> b+a03 (8 oldest) done;
        // a47 reads fly under the first MFMA cluster.
        asm volatile("s_waitcnt lgkmcnt(4)" ::: "memory");
        __builtin_amdgcn_sched_barrier(0);
        __builtin_amdgcn_s_setprio(1);
        #pragma unroll
        for (int mt = 0; mt < 4; ++mt)
            #pragma unroll
            for (int nt = 0; nt < 4; ++nt)
                acc[mt][nt] = MFMA16(a03[mt], b[nt], acc[mt][nt]);
        __builtin_amdgcn_s_setprio(0);
        asm volatile("s_waitcnt lgkmcnt(0)" ::: "memory");
        __builtin_amdgcn_sched_barrier(0);
        __builtin_amdgcn_s_setprio(1);
        #pragma unroll
        for (int mt = 0; mt < 4; ++mt)
            #pragma unroll
            for (int nt = 0; nt < 4; ++nt)
                acc[mt + 4][nt] = MFMA16(a47[mt], b[nt], acc[mt + 4][nt]);
        __builtin_amdgcn_s_setprio(0);
        __builtin_amdgcn_s_barrier();   // close: reads done before restage
        asm volatile("" ::: "memory");
    }
}

// ---------------------------------------------------------------------------
// Kernel: qkv = xb @ WqkvT^T + bqkv
// q,k stored [b,h,t,64]; v stored TRANSPOSED [b,h,64,t]
// grid (32, 12), block 512.
// ---------------------------------------------------------------------------
__global__ __launch_bounds__(512, 2) void qkv_gemm(
    const u16* __restrict__ xb, const u16* __restrict__ Wt,
    const float* __restrict__ bias, u16* __restrict__ qkvb)
{
    __shared__ u16 L[2 * BUF32];   // 64 KB -> 2 blocks/CU
    const int m0 = blockIdx.x * 256, n0 = blockIdx.y * 256;
    const int tid = threadIdx.x;
    f32x4 acc[8][4] = {};
    gemm_mainloop32(xb, Wt, L, m0, n0, tid, acc);

    const int lane = tid & 63, w = tid >> 6;
    const int lr = lane & 15, quad = lane >> 4;
    const int wm = w >> 2, wn = w & 3;
    const int which = n0 >> 10;  // uniform per block (256 divides 1024)
    float bv[4];
    #pragma unroll
    for (int nt = 0; nt < 4; ++nt) bv[nt] = bias[n0 + wn * 64 + nt * 16 + lr];

    if (which == 2) {
        // V: transposed store [b,h,d,t], 4 regs = 4 consecutive t -> b64
        u16* vT = qkvb + (size_t)2 * 8388608;
        #pragma unroll
        for (int nt = 0; nt < 4; ++nt) {
            int n = n0 + wn * 64 + nt * 16 + lr;
            int hh = (n >> 6) & 15, d = n & 63;
            #pragma unroll
            for (int mt = 0; mt < 8; ++mt) {
                int mbase = m0 + wm * 128 + mt * 16 + quad * 4;
                int b_idx = mbase >> 11, t0 = mbase & 2047;
                short4v o4;
                #pragma unroll
                for (int reg = 0; reg < 4; ++reg)
                    o4[reg] = (short)f2bf(acc[mt][nt][reg] + bv[nt]);
                *(short4v*)&vT[((size_t)(b_idx * 16 + hh) * 64 + d) * 2048 + t0] = o4;
            }
        }
    } else {
        u16* dst = qkvb + (size_t)which * 8388608;
        #pragma unroll
        for (int mt = 0; mt < 8; ++mt)
          #pragma unroll
          for (int nt = 0; nt < 4; ++nt) {
            int n = n0 + wn * 64 + nt * 16 + lr;
            int hh = (n >> 6) & 15, d = n & 63;
            #pragma unroll
            for (int reg = 0; reg < 4; ++reg) {
                int m = m0 + wm * 128 + mt * 16 + quad * 4 + reg;
                int b_idx = m >> 11, t_idx = m & 2047;
                dst[(((size_t)(b_idx * 16 + hh) * 2048 + t_idx) << 6) + d] =
                    f2bf(acc[mt][nt][reg] + bv[nt]);
            }
          }
    }
}

// ===========================================================================
// out_gemm mainloop (round-1 PROVEN): 256x128 / BK=64, 8 waves (4M x 2N),
// 3-buffer LDS ring, counted vmcnt(12)/(6)/(0). Grid 32x8 = 256. Unchanged.
// ===========================================================================
#define KT16 16  // K=1024 / BK=64

__device__ __forceinline__ void stage_tile256(
    const u16* __restrict__ A, const u16* __restrict__ Bt,
    u16* Lb, int m0, int n0, int k0, int w, int grow, int gchunk)
{
    #pragma unroll
    for (int r = 0; r < 4; ++r) {
        int rb = w * 4 + r;   // 32 rowblocks of A
        async16(Lb + rb * 512,
                A + (size_t)(m0 + rb * 8 + grow) * 1024 + k0 + gchunk * 8);
    }
    #pragma unroll
    for (int r = 0; r < 2; ++r) {
        int rb = w * 2 + r;   // 16 rowblocks of B
        async16(Lb + 16384 + rb * 512,
                Bt + (size_t)(n0 + rb * 8 + grow) * 1024 + k0 + gchunk * 8);
    }
}

__device__ __forceinline__ void gemm_mainloop256(
    const u16* __restrict__ A, const u16* __restrict__ Bt,
    u16* L, int m0, int n0, int tid, f32x4 acc[4][4])
{
    const int lane = tid & 63, w = tid >> 6;
    const int lr = lane & 15, quad = lane >> 4;
    const int wm = w >> 1, wn = w & 1;
    const int grow = lane & 7, gchunk = lane >> 3;

    // prologue: stage T0, T1
    stage_tile256(A, Bt, L,         m0, n0, 0,  w, grow, gchunk);
    stage_tile256(A, Bt, L + 24576, m0, n0, 64, w, grow, gchunk);

    u16* Lc = L;              // compute buffer (tile t)
    u16* Ls = L + 49152;      // stage buffer (tile t+2)
    u16* const Lend = L + 73728;

    for (int t = 0; t < KT16; ++t) {
        if (t < KT16 - 2)
            stage_tile256(A, Bt, Ls, m0, n0, (t + 2) * 64, w, grow, gchunk);

        if (t < KT16 - 2)       asm volatile("s_waitcnt vmcnt(12)" ::: "memory");
        else if (t == KT16 - 2) asm volatile("s_waitcnt vmcnt(6)"  ::: "memory");
        else                    asm volatile("s_waitcnt vmcnt(0)"  ::: "memory");
        __builtin_amdgcn_s_barrier();
        asm volatile("" ::: "memory");

        const u16* As = Lc;
        const u16* Bs = Lc + 16384;
        __builtin_amdgcn_s_setprio(1);
        #pragma unroll
        for (int kk = 0; kk < 2; ++kk) {
            ushort8 a[4], b[4];
            #pragma unroll
            for (int mt = 0; mt < 4; ++mt) {
                int rb = wm * 8 + mt * 2 + (lr >> 3);
                a[mt] = *(const ushort8*)&As[rb * 512 + (kk * 4 + quad) * 64 + (lr & 7) * 8];
            }
            #pragma unroll
            for (int nt = 0; nt < 4; ++nt) {
                int rb = wn * 8 + nt * 2 + (lr >> 3);
                b[nt] = *(const ushort8*)&Bs[rb * 512 + (kk * 4 + quad) * 64 + (lr & 7) * 8];
            }
            #pragma unroll
            for (int mt = 0; mt < 4; ++mt)
                #pragma unroll
                for (int nt = 0; nt < 4; ++nt)
                    acc[mt][nt] = MFMA16(a[mt], b[nt], acc[mt][nt]);
        }
        __builtin_amdgcn_s_setprio(0);
        asm volatile("" ::: "memory");
        __builtin_amdgcn_s_barrier();
        asm volatile("" ::: "memory");

        Lc += 24576; if (Lc == Lend) Lc = L;
        Ls += 24576; if (Ls == Lend) Ls = L;
    }
}

// ---------------------------------------------------------------------------
// Kernel: out = attn_o @ WoutT^T + bout (fp32 out)
// grid (32, 8), block 512.
// ---------------------------------------------------------------------------
__global__ __launch_bounds__(512, 2) void out_gemm(
    const u16* __restrict__ A, const u16* __restrict__ Wt,
    const float* __restrict__ bias, float* __restrict__ out)
{
    __shared__ u16 L[73728];
    const int m0 = blockIdx.x * 256, n0 = blockIdx.y * 128;
    const int tid = threadIdx.x;
    f32x4 acc[4][4] = {};
    gemm_mainloop256(A, Wt, L, m0, n0, tid, acc);

    const int lane = tid & 63, w = tid >> 6;
    const int lr = lane & 15, quad = lane >> 4;
    const int wm = w >> 1, wn = w & 1;
    float bv[4];
    #pragma unroll
    for (int nt = 0; nt < 4; ++nt) bv[nt] = bias[n0 + wn * 64 + nt * 16 + lr];
    #pragma unroll
    for (int mt = 0; mt < 4; ++mt)
      #pragma unroll
      for (int nt = 0; nt < 4; ++nt)
        #pragma unroll
        for (int reg = 0; reg < 4; ++reg) {
            int m = m0 + wm * 64 + mt * 16 + quad * 4 + reg;
            int n = n0 + wn * 64 + nt * 16 + lr;
            out[(size_t)m * 1024 + n] = acc[mt][nt][reg] + bv[nt];
        }
}

// ---------------------------------------------------------------------------
// Flash attention — round-7 PROVEN structure (pass-fusion reverted: it
// doubled Ps bank conflicts and halved occupancy, 271->284us).
// NEW this round: l (softmax denominator) via the MATRIX pipe — an extra
// f32x4 accumulator fed by MFMA16(pa, ones, l_acc): C[q][*] = sum_k P[q][k].
// C-row = quad*4+reg matches o_acc rows exactly, so:
//  - removes the 16-add + 2-shuffle rs reduction (~22 VALU inst/iter)
//  - removes the 4 epilogue broadcast shuffles (1/l_acc[reg] direct)
//  - cost: +2 MFMA/iter reusing the already-loaded pa (~10 matrix cyc)
// Deferred-max rescale scales l_acc by the same broadcast alpha as o_acc.
// l summed from the same bf16 P that PV consumes (more self-consistent).
// ---------------------------------------------------------------------------
__global__ __launch_bounds__(256) void attn_kernel(
    const u16* __restrict__ qkvb, u16* __restrict__ o_ws)
{
    const int orig = blockIdx.x + 16 * (blockIdx.y + 16 * blockIdx.z);  // 0..1023
    const int work = (orig & 7) * 128 + (orig >> 3);   // bijective (1024 % 8 == 0)
    const int p = work & 15, h = (work >> 4) & 15, b = work >> 8;
    const size_t bh = (size_t)(b * 16 + h) * 131072;
    const u16* Qb = qkvb + bh;
    const u16* Kb = qkvb + 8388608 + bh;
    const u16* Vt = qkvb + 2 * 8388608 + bh;   // [64][2048]
    __shared__ u16 Ks[2][4096];   // [rb(8)][chunk(8)][row(8)][8]
    __shared__ u16 Vts[4096];     // same swizzle, rows = d
    __shared__ u16 Ps[64 * 72];
    const int tid = threadIdx.x, lane = tid & 63, w = tid >> 6;
    const int lr = lane & 15, quad = lane >> 4;
    const int grow = lane & 7, gchunk = lane >> 3;
    const float kscale = 0.125f * 1.44269504f;  // scale * log2(e)
    ushort8 ones8;
    #pragma unroll
    for (int i = 0; i < 8; ++i) ones8[i] = 0x3F80;   // bf16 1.0

    for (int pass = 0; pass < 2; ++pass) {
        const int qt = pass ? (31 - p) : p;
        // Q A-fragments straight from global (contiguous k-chunks)
        ushort8 qf[2];
        {
            const u16* qr = Qb + (size_t)(qt * 64 + w * 16 + lr) * 64 + quad * 8;
            qf[0] = *(const ushort8*)qr;
            qf[1] = *(const ushort8*)(qr + 32);
        }
        f32x4 o_acc[4] = {};
        f32x4 l_acc = {};                    // denominator, same row-layout as o_acc
        float m_i = -1e30f;                  // lane-local (scaled domain)
        const int qrow = w * 16 + lr;        // in-tile q row this lane reduces
        const int bsrc = (lane & 48) + ((lane >> 4) << 2);  // quad*16 + quad*4

        __syncthreads();  // prev pass's LDS reads done
        #pragma unroll
        for (int r = 0; r < 2; ++r) {   // stage K(0)
            int rb = w * 2 + r;
            async16(&Ks[0][rb * 512], Kb + (size_t)(rb * 8 + grow) * 64 + gchunk * 8);
        }

        for (int kt = 0; kt <= qt; ++kt) {
            const int buf = kt & 1;
            __syncthreads();  // barrier A: K(kt) staged; prev iter's PV reads done

            // prefetch K(kt+1) into other buffer; stage V(kt) just-in-time
            #pragma unroll
            for (int r = 0; r < 2; ++r) {
                int rb = w * 2 + r;
                if (kt < qt)
                    async16(&Ks[buf ^ 1][rb * 512],
                            Kb + (size_t)((kt + 1) * 64 + rb * 8 + grow) * 64 + gchunk * 8);
                async16(&Vts[rb * 512],
                        Vt + (size_t)(rb * 8 + grow) * 2048 + kt * 64 + gchunk * 8);
            }

            // S^T = K Q^T: C rows = k-cols (quad*4+reg), C cols = q (lr).
            f32x4 s[4] = {};
            #pragma unroll
            for (int nt = 0; nt < 4; ++nt)
                #pragma unroll
                for (int kk = 0; kk < 2; ++kk) {
                    ushort8 bb = *(ushort8*)&Ks[buf][(nt * 2 + (lr >> 3)) * 512 +
                                                     (kk * 4 + quad) * 64 + (lr & 7) * 8];
                    s[nt] = MFMA16(bb, qf[kk], s[nt]);
                }
            // causal mask on RAW scores (diagonal tile only); scale folds later
            if (kt == qt) {
                #pragma unroll
                for (int nt = 0; nt < 4; ++nt)
                    #pragma unroll
                    for (int reg = 0; reg < 4; ++reg) {
                        int kc = nt * 16 + quad * 4 + reg;
                        if (kc > qrow) s[nt][reg] = -1e30f;
                    }
            }
            // row max: 15 in-lane + 2 shuffles (raw), one mult to scaled domain
            float mx = -1e30f;
            #pragma unroll
            for (int nt = 0; nt < 4; ++nt)
                #pragma unroll
                for (int reg = 0; reg < 4; ++reg) mx = fmaxf(mx, s[nt][reg]);
            mx = fmaxf(mx, __shfl_xor(mx, 16, 64));
            mx = fmaxf(mx, __shfl_xor(mx, 32, 64));
            float mxs = mx * kscale;
            // defer-max (T13): only rescale when the max actually moved
            if (!__all(mxs <= m_i + 8.0f)) {
                float mnew = fmaxf(m_i, mxs);
                float alpha = EXP2(m_i - mnew);
                m_i = mnew;
                #pragma unroll
                for (int reg = 0; reg < 4; ++reg) {
                    float ar = __shfl(alpha, bsrc + reg, 64);  // alpha of row quad*4+reg
                    l_acc[reg] *= ar;
                    #pragma unroll
                    for (int dt = 0; dt < 4; ++dt) o_acc[dt][reg] *= ar;
                }
            }
            // P = exp2(s*kscale - m_i) via fmaf (no VALU row-sum: l via MFMA)
            float p4[4][4];
            #pragma unroll
            for (int nt = 0; nt < 4; ++nt)
                #pragma unroll
                for (int reg = 0; reg < 4; ++reg)
                    p4[nt][reg] = EXP2(fmaf(s[nt][reg], kscale, -m_i));
            // P^T -> Ps: packed cvt, 4 f32 -> one b64 per nt (own rows only)
            #pragma unroll
            for (int nt = 0; nt < 4; ++nt) {
                unsigned lo = pk2(p4[nt][0], p4[nt][1]);
                unsigned hi = pk2(p4[nt][2], p4[nt][3]);
                unsigned long long pk = ((unsigned long long)hi << 32) | lo;
                *(unsigned long long*)&Ps[qrow * 72 + nt * 16 + quad * 4] = pk;
            }

            __syncthreads();  // barrier B: Ps ordered+visible; V(kt) drained

            // O += P V; l += P 1 (matrix pipe, reusing pa)
            #pragma unroll
            for (int kk = 0; kk < 2; ++kk) {
                ushort8 pa = *(ushort8*)&Ps[(w * 16 + lr) * 72 + kk * 32 + quad * 8];
                #pragma unroll
                for (int dt = 0; dt < 4; ++dt) {
                    ushort8 vb = *(ushort8*)&Vts[(dt * 2 + (lr >> 3)) * 512 +
                                                 (kk * 4 + quad) * 64 + (lr & 7) * 8];
                    o_acc[dt] = MFMA16(pa, vb, o_acc[dt]);
                }
                l_acc = MFMA16(pa, ones8, l_acc);
            }
        }

        // epilogue: normalize — l_acc rows match o_acc rows (no broadcast)
        float rl[4];
        #pragma unroll
        for (int reg = 0; reg < 4; ++reg) rl[reg] = 1.0f / l_acc[reg];
        #pragma unroll
        for (int dt = 0; dt < 4; ++dt)
            #pragma unroll
            for (int reg = 0; reg < 4; ++reg) {
                int row = w * 16 + quad * 4 + reg;
                int tq = qt * 64 + row;
                o_ws[((size_t)(b * 2048 + tq) << 10) + h * 64 + dt * 16 + lr] =
                    f2bf(o_acc[dt][reg] * rl[reg]);
            }
    }
}

extern "C" void kernel_launch(void* const* d_in, const int* in_sizes, int n_in,
                              void* d_out, int out_size, void* d_ws, size_t ws_size,
                              hipStream_t stream)
{
    const float* x    = (const float*)d_in[0];
    const float* Wqkv = (const float*)d_in[1];
    const float* bqkv = (const float*)d_in[2];
    const float* Wout = (const float*)d_in[3];
    const float* bout = (const float*)d_in[4];
    float* out = (float*)d_out;

    u16* qkvb = (u16*)d_ws;                    // q | k | vT, 3 * 8388608 elems
    u16* xb   = qkvb + (size_t)3 * 8388608;    // 8388608 elems; reused as attn_o
    u16* wT   = qkvb + (size_t)4 * 8388608;    // up to 3072*1024 elems
    u16* attn_o = xb;

    convert_bf16<<<4096, 256, 0, stream>>>(x, xb);
    transpose_convert<<<dim3(16, 48), 256, 0, stream>>>(Wqkv, wT, 3072, 1024);
    qkv_gemm<<<dim3(32, 12), 512, 0, stream>>>(xb, wT, bqkv, qkvb);
    attn_kernel<<<dim3(16, 16, 4), 256, 0, stream>>>(qkvb, attn_o);
    transpose_convert<<<dim3(16, 16), 256, 0, stream>>>(Wout, wT, 1024, 1024);
    out_gemm<<<dim3(32, 8), 512, 0, stream>>>(attn_o, wT, bout, out);
}

// Round 11
// 272.341 us; speedup vs baseline: 1.0792x; 1.0792x over previous
//
#include <hip/hip_runtime.h>
#include <hip/hip_bf16.h>
#include <stdint.h>

typedef unsigned short u16;
typedef __bf16 bf16x8 __attribute__((ext_vector_type(8)));
typedef float f32x4 __attribute__((ext_vector_type(4)));
typedef u16 ushort8 __attribute__((ext_vector_type(8)));
typedef short short4v __attribute__((ext_vector_type(4)));

__device__ __forceinline__ u16 f2bf(float f) {
    unsigned int u = __builtin_bit_cast(unsigned int, f);
    u += 0x7fffu + ((u >> 16) & 1u);
    return (u16)(u >> 16);
}

// 2x f32 -> packed bf16 (RNE) via the HIP intrinsic (proven round 7).
__device__ __forceinline__ unsigned pk2(float a, float b) {
    __hip_bfloat162 h = __float22bfloat162_rn(float2{a, b});
    unsigned u;
    __builtin_memcpy(&u, &h, 4);
    return u;
}

#define MFMA16(a, b, c) __builtin_amdgcn_mfma_f32_16x16x32_bf16( \
    __builtin_bit_cast(bf16x8, a), __builtin_bit_cast(bf16x8, b), c, 0, 0, 0)

#if defined(__has_builtin)
#if __has_builtin(__builtin_amdgcn_exp2f)
#define EXP2(x) __builtin_amdgcn_exp2f(x)
#endif
#endif
#ifndef EXP2
#define EXP2(x) __expf((x) * 0.69314718f)
#endif

// async global->LDS, 16B per lane. LDS dest = wave-uniform base + lane*16.
__device__ __forceinline__ void async16(void* lds, const void* g) {
    __builtin_amdgcn_global_load_lds(
        (const __attribute__((address_space(1))) unsigned int*)(uintptr_t)g,
        (__attribute__((address_space(3))) unsigned int*)(unsigned int)(uintptr_t)lds,
        16, 0, 0);
}

// ---------------------------------------------------------------------------
// convert fp32 -> bf16, 8 elems/thread
// ---------------------------------------------------------------------------
__global__ __launch_bounds__(256) void convert_bf16(
    const float* __restrict__ src, u16* __restrict__ dst)
{
    int i = blockIdx.x * 256 + threadIdx.x;
    float4 f0 = ((const float4*)src)[i * 2];
    float4 f1 = ((const float4*)src)[i * 2 + 1];
    ushort8 v;
    v[0]=f2bf(f0.x); v[1]=f2bf(f0.y); v[2]=f2bf(f0.z); v[3]=f2bf(f0.w);
    v[4]=f2bf(f1.x); v[5]=f2bf(f1.y); v[6]=f2bf(f1.z); v[7]=f2bf(f1.w);
    ((ushort8*)dst)[i] = v;
}

// ---------------------------------------------------------------------------
// transpose+convert: src fp32 [K][N] -> dst bf16 [N][K]; 64x64 tiles
// ---------------------------------------------------------------------------
__global__ __launch_bounds__(256) void transpose_convert(
    const float* __restrict__ src, u16* __restrict__ dst, int N, int K)
{
    __shared__ u16 T[64][68];
    const int k0 = blockIdx.x * 64, n0 = blockIdx.y * 64;
    const int tid = threadIdx.x;
    const int rr = tid >> 4, cc = (tid & 15) * 4;
    #pragma unroll
    for (int rnd = 0; rnd < 4; ++rnd) {
        int r = rr + rnd * 16;
        float4 f = *(const float4*)&src[(size_t)(k0 + r) * N + n0 + cc];
        u16 v[4] = {f2bf(f.x), f2bf(f.y), f2bf(f.z), f2bf(f.w)};
        *(unsigned long long*)&T[r][cc] = *(unsigned long long*)v;
    }
    __syncthreads();
    #pragma unroll
    for (int rnd = 0; rnd < 4; ++rnd) {
        int rn = rr + rnd * 16;
        u16 v[4];
        #pragma unroll
        for (int j = 0; j < 4; ++j) v[j] = T[cc + j][rn];
        *(unsigned long long*)&dst[(size_t)(n0 + rn) * K + k0 + cc] =
            *(unsigned long long*)v;
    }
}

// ===========================================================================
// qkv mainloop: 256x256 / BK=32, 512 threads = 8 waves (2M x 4N).
// 2 x 32KB LDS -> 2 blocks/CU. (round-4 version, best so far: 85us)
// ===========================================================================
#define NT32 32      // K=1024 / BK=32
#define BUF32 16384  // u16 per buffer: A 8192 (256x32) + B 8192 (256x32)

__device__ __forceinline__ void stage32(
    const u16* __restrict__ A, const u16* __restrict__ Bt,
    u16* Lb, int m0, int n0, int k0, int w, int lane)
{
    const int rbl = lane >> 5;          // which rb of the wave's pair
    const int chunk = (lane >> 3) & 3;  // k-chunk of 8 u16
    const int row = lane & 7;
    #pragma unroll
    for (int r = 0; r < 2; ++r) {
        int rb = w * 4 + r * 2 + rbl;
        async16(Lb + (w * 4 + r * 2) * 256,
                A + (size_t)(m0 + rb * 8 + row) * 1024 + k0 + chunk * 8);
    }
    #pragma unroll
    for (int r = 0; r < 2; ++r) {
        int rb = w * 4 + r * 2 + rbl;
        async16(Lb + 8192 + (w * 4 + r * 2) * 256,
                Bt + (size_t)(n0 + rb * 8 + row) * 1024 + k0 + chunk * 8);
    }
}

__device__ __forceinline__ void gemm_mainloop32(
    const u16* __restrict__ A, const u16* __restrict__ Bt,
    u16* L, int m0, int n0, int tid, f32x4 acc[8][4])
{
    const int lane = tid & 63, w = tid >> 6;
    const int lr = lane & 15, quad = lane >> 4;
    const int wm = w >> 2, wn = w & 3;
    const int arb = wm * 16 + (lr >> 3);   // + mt*2
    const int brb = wn * 8 + (lr >> 3);    // + nt*2
    const int foff = quad * 64 + (lr & 7) * 8;

    // prologue: stage T0, drain, barrier
    stage32(A, Bt, L, m0, n0, 0, w, lane);
    asm volatile("s_waitcnt vmcnt(0)" ::: "memory");
    __builtin_amdgcn_s_barrier();
    asm volatile("" ::: "memory");

    #pragma unroll 2
    for (int t = 0; t < NT32; ++t) {
        const u16* As = L + (t & 1) * BUF32;
        const u16* Bs = As + 8192;

        // stage next tile; counted wait: tile t landed, t+1 stays in flight
        if (t + 1 < NT32) {
            stage32(A, Bt, L + ((t + 1) & 1) * BUF32, m0, n0, (t + 1) * 32,
                    w, lane);
            asm volatile("s_waitcnt vmcnt(4)" ::: "memory");
        } else {
            asm volatile("s_waitcnt vmcnt(0)" ::: "memory");
        }
        __builtin_amdgcn_s_barrier();   // open: buf[t&1] visible to all waves
        asm volatile("" ::: "memory");

        ushort8 b[4], a03[4], a47[4];
        #pragma unroll
        for (int nt = 0; nt < 4; ++nt)
            b[nt] = *(const ushort8*)&Bs[(brb + nt * 2) * 256 + foff];
        #pragma unroll
        for (int mt = 0; mt < 4; ++mt)
            a03[mt] = *(const ushort8*)&As[(arb + mt * 2) * 256 + foff];
        __builtin_amdgcn_sched_barrier(0);   // pin issue order: b+a03 first
        #pragma unroll
        for (int mt = 0; mt < 4; ++mt)
            a47[mt] = *(const ushort8*)&As[(arb + (mt + 4) * 2) * 256 + foff];
        // counted lgkm: 12 issued, wait to <=4 -> b+a03 (8 oldest) done;
        // a47 reads fly under the first MFMA cluster.
        asm volatile("s_waitcnt lgkmcnt(4)" ::: "memory");
        __builtin_amdgcn_sched_barrier(0);
        __builtin_amdgcn_s_setprio(1);
        #pragma unroll
        for (int mt = 0; mt < 4; ++mt)
            #pragma unroll
            for (int nt = 0; nt < 4; ++nt)
                acc[mt][nt] = MFMA16(a03[mt], b[nt], acc[mt][nt]);
        __builtin_amdgcn_s_setprio(0);
        asm volatile("s_waitcnt lgkmcnt(0)" ::: "memory");
        __builtin_amdgcn_sched_barrier(0);
        __builtin_amdgcn_s_setprio(1);
        #pragma unroll
        for (int mt = 0; mt < 4; ++mt)
            #pragma unroll
            for (int nt = 0; nt < 4; ++nt)
                acc[mt + 4][nt] = MFMA16(a47[mt], b[nt], acc[mt + 4][nt]);
        __builtin_amdgcn_s_setprio(0);
        __builtin_amdgcn_s_barrier();   // close: reads done before restage
        asm volatile("" ::: "memory");
    }
}

// ---------------------------------------------------------------------------
// Kernel: qkv = xb @ WqkvT^T + bqkv
// q,k stored [b,h,t,64]; v stored TRANSPOSED [b,h,64,t]
// grid (32, 12), block 512.
// ---------------------------------------------------------------------------
__global__ __launch_bounds__(512, 2) void qkv_gemm(
    const u16* __restrict__ xb, const u16* __restrict__ Wt,
    const float* __restrict__ bias, u16* __restrict__ qkvb)
{
    __shared__ u16 L[2 * BUF32];   // 64 KB -> 2 blocks/CU
    const int m0 = blockIdx.x * 256, n0 = blockIdx.y * 256;
    const int tid = threadIdx.x;
    f32x4 acc[8][4] = {};
    gemm_mainloop32(xb, Wt, L, m0, n0, tid, acc);

    const int lane = tid & 63, w = tid >> 6;
    const int lr = lane & 15, quad = lane >> 4;
    const int wm = w >> 2, wn = w & 3;
    const int which = n0 >> 10;  // uniform per block (256 divides 1024)
    float bv[4];
    #pragma unroll
    for (int nt = 0; nt < 4; ++nt) bv[nt] = bias[n0 + wn * 64 + nt * 16 + lr];

    if (which == 2) {
        // V: transposed store [b,h,d,t], 4 regs = 4 consecutive t -> b64
        u16* vT = qkvb + (size_t)2 * 8388608;
        #pragma unroll
        for (int nt = 0; nt < 4; ++nt) {
            int n = n0 + wn * 64 + nt * 16 + lr;
            int hh = (n >> 6) & 15, d = n & 63;
            #pragma unroll
            for (int mt = 0; mt < 8; ++mt) {
                int mbase = m0 + wm * 128 + mt * 16 + quad * 4;
                int b_idx = mbase >> 11, t0 = mbase & 2047;
                short4v o4;
                #pragma unroll
                for (int reg = 0; reg < 4; ++reg)
                    o4[reg] = (short)f2bf(acc[mt][nt][reg] + bv[nt]);
                *(short4v*)&vT[((size_t)(b_idx * 16 + hh) * 64 + d) * 2048 + t0] = o4;
            }
        }
    } else {
        u16* dst = qkvb + (size_t)which * 8388608;
        #pragma unroll
        for (int mt = 0; mt < 8; ++mt)
          #pragma unroll
          for (int nt = 0; nt < 4; ++nt) {
            int n = n0 + wn * 64 + nt * 16 + lr;
            int hh = (n >> 6) & 15, d = n & 63;
            #pragma unroll
            for (int reg = 0; reg < 4; ++reg) {
                int m = m0 + wm * 128 + mt * 16 + quad * 4 + reg;
                int b_idx = m >> 11, t_idx = m & 2047;
                dst[(((size_t)(b_idx * 16 + hh) * 2048 + t_idx) << 6) + d] =
                    f2bf(acc[mt][nt][reg] + bv[nt]);
            }
          }
    }
}

// ===========================================================================
// out_gemm mainloop (round-1 PROVEN): 256x128 / BK=64, 8 waves (4M x 2N),
// 3-buffer LDS ring, counted vmcnt(12)/(6)/(0). Grid 32x8 = 256. Unchanged.
// ===========================================================================
#define KT16 16  // K=1024 / BK=64

__device__ __forceinline__ void stage_tile256(
    const u16* __restrict__ A, const u16* __restrict__ Bt,
    u16* Lb, int m0, int n0, int k0, int w, int grow, int gchunk)
{
    #pragma unroll
    for (int r = 0; r < 4; ++r) {
        int rb = w * 4 + r;   // 32 rowblocks of A
        async16(Lb + rb * 512,
                A + (size_t)(m0 + rb * 8 + grow) * 1024 + k0 + gchunk * 8);
    }
    #pragma unroll
    for (int r = 0; r < 2; ++r) {
        int rb = w * 2 + r;   // 16 rowblocks of B
        async16(Lb + 16384 + rb * 512,
                Bt + (size_t)(n0 + rb * 8 + grow) * 1024 + k0 + gchunk * 8);
    }
}

__device__ __forceinline__ void gemm_mainloop256(
    const u16* __restrict__ A, const u16* __restrict__ Bt,
    u16* L, int m0, int n0, int tid, f32x4 acc[4][4])
{
    const int lane = tid & 63, w = tid >> 6;
    const int lr = lane & 15, quad = lane >> 4;
    const int wm = w >> 1, wn = w & 1;
    const int grow = lane & 7, gchunk = lane >> 3;

    // prologue: stage T0, T1
    stage_tile256(A, Bt, L,         m0, n0, 0,  w, grow, gchunk);
    stage_tile256(A, Bt, L + 24576, m0, n0, 64, w, grow, gchunk);

    u16* Lc = L;              // compute buffer (tile t)
    u16* Ls = L + 49152;      // stage buffer (tile t+2)
    u16* const Lend = L + 73728;

    for (int t = 0; t < KT16; ++t) {
        if (t < KT16 - 2)
            stage_tile256(A, Bt, Ls, m0, n0, (t + 2) * 64, w, grow, gchunk);

        if (t < KT16 - 2)       asm volatile("s_waitcnt vmcnt(12)" ::: "memory");
        else if (t == KT16 - 2) asm volatile("s_waitcnt vmcnt(6)"  ::: "memory");
        else                    asm volatile("s_waitcnt vmcnt(0)"  ::: "memory");
        __builtin_amdgcn_s_barrier();
        asm volatile("" ::: "memory");

        const u16* As = Lc;
        const u16* Bs = Lc + 16384;
        __builtin_amdgcn_s_setprio(1);
        #pragma unroll
        for (int kk = 0; kk < 2; ++kk) {
            ushort8 a[4], b[4];
            #pragma unroll
            for (int mt = 0; mt < 4; ++mt) {
                int rb = wm * 8 + mt * 2 + (lr >> 3);
                a[mt] = *(const ushort8*)&As[rb * 512 + (kk * 4 + quad) * 64 + (lr & 7) * 8];
            }
            #pragma unroll
            for (int nt = 0; nt < 4; ++nt) {
                int rb = wn * 8 + nt * 2 + (lr >> 3);
                b[nt] = *(const ushort8*)&Bs[rb * 512 + (kk * 4 + quad) * 64 + (lr & 7) * 8];
            }
            #pragma unroll
            for (int mt = 0; mt < 4; ++mt)
                #pragma unroll
                for (int nt = 0; nt < 4; ++nt)
                    acc[mt][nt] = MFMA16(a[mt], b[nt], acc[mt][nt]);
        }
        __builtin_amdgcn_s_setprio(0);
        asm volatile("" ::: "memory");
        __builtin_amdgcn_s_barrier();
        asm volatile("" ::: "memory");

        Lc += 24576; if (Lc == Lend) Lc = L;
        Ls += 24576; if (Ls == Lend) Ls = L;
    }
}

// ---------------------------------------------------------------------------
// Kernel: out = attn_o @ WoutT^T + bout (fp32 out)
// grid (32, 8), block 512.
// ---------------------------------------------------------------------------
__global__ __launch_bounds__(512, 2) void out_gemm(
    const u16* __restrict__ A, const u16* __restrict__ Wt,
    const float* __restrict__ bias, float* __restrict__ out)
{
    __shared__ u16 L[73728];
    const int m0 = blockIdx.x * 256, n0 = blockIdx.y * 128;
    const int tid = threadIdx.x;
    f32x4 acc[4][4] = {};
    gemm_mainloop256(A, Wt, L, m0, n0, tid, acc);

    const int lane = tid & 63, w = tid >> 6;
    const int lr = lane & 15, quad = lane >> 4;
    const int wm = w >> 1, wn = w & 1;
    float bv[4];
    #pragma unroll
    for (int nt = 0; nt < 4; ++nt) bv[nt] = bias[n0 + wn * 64 + nt * 16 + lr];
    #pragma unroll
    for (int mt = 0; mt < 4; ++mt)
      #pragma unroll
      for (int nt = 0; nt < 4; ++nt)
        #pragma unroll
        for (int reg = 0; reg < 4; ++reg) {
            int m = m0 + wm * 64 + mt * 16 + quad * 4 + reg;
            int n = n0 + wn * 64 + nt * 16 + lr;
            out[(size_t)m * 1024 + n] = acc[mt][nt][reg] + bv[nt];
        }
}

// ---------------------------------------------------------------------------
// Flash attention — round-7 PROVEN kernel, VERBATIM (best total: 271.3us).
// 2-barrier structure; swapped QK^T in-register softmax; defer-max;
// packed-cvt P store; fmaf scale fold; VALU rs-sum + shuffle l (the
// l-via-MFMA variant of round 9 regressed: serial accumulator chain).
// ---------------------------------------------------------------------------
__global__ __launch_bounds__(256) void attn_kernel(
    const u16* __restrict__ qkvb, u16* __restrict__ o_ws)
{
    const int orig = blockIdx.x + 16 * (blockIdx.y + 16 * blockIdx.z);  // 0..1023
    const int work = (orig & 7) * 128 + (orig >> 3);   // bijective (1024 % 8 == 0)
    const int p = work & 15, h = (work >> 4) & 15, b = work >> 8;
    const size_t bh = (size_t)(b * 16 + h) * 131072;
    const u16* Qb = qkvb + bh;
    const u16* Kb = qkvb + 8388608 + bh;
    const u16* Vt = qkvb + 2 * 8388608 + bh;   // [64][2048]
    __shared__ u16 Ks[2][4096];   // [rb(8)][chunk(8)][row(8)][8]
    __shared__ u16 Vts[4096];     // same swizzle, rows = d
    __shared__ u16 Ps[64 * 72];
    const int tid = threadIdx.x, lane = tid & 63, w = tid >> 6;
    const int lr = lane & 15, quad = lane >> 4;
    const int grow = lane & 7, gchunk = lane >> 3;
    const float kscale = 0.125f * 1.44269504f;  // scale * log2(e)

    for (int pass = 0; pass < 2; ++pass) {
        const int qt = pass ? (31 - p) : p;
        // Q A-fragments straight from global (contiguous k-chunks)
        ushort8 qf[2];
        {
            const u16* qr = Qb + (size_t)(qt * 64 + w * 16 + lr) * 64 + quad * 8;
            qf[0] = *(const ushort8*)qr;
            qf[1] = *(const ushort8*)(qr + 32);
        }
        f32x4 o_acc[4] = {};
        float m_i = -1e30f, l_i = 0.f;       // lane-local (scaled domain)
        const int qrow = w * 16 + lr;        // in-tile q row this lane reduces
        const int bsrc = (lane & 48) + ((lane >> 4) << 2);  // quad*16 + quad*4

        __syncthreads();  // prev pass's LDS reads done
        #pragma unroll
        for (int r = 0; r < 2; ++r) {   // stage K(0)
            int rb = w * 2 + r;
            async16(&Ks[0][rb * 512], Kb + (size_t)(rb * 8 + grow) * 64 + gchunk * 8);
        }

        for (int kt = 0; kt <= qt; ++kt) {
            const int buf = kt & 1;
            __syncthreads();  // barrier A: K(kt) staged; prev iter's PV reads done

            // prefetch K(kt+1) into other buffer; stage V(kt) just-in-time
            #pragma unroll
            for (int r = 0; r < 2; ++r) {
                int rb = w * 2 + r;
                if (kt < qt)
                    async16(&Ks[buf ^ 1][rb * 512],
                            Kb + (size_t)((kt + 1) * 64 + rb * 8 + grow) * 64 + gchunk * 8);
                async16(&Vts[rb * 512],
                        Vt + (size_t)(rb * 8 + grow) * 2048 + kt * 64 + gchunk * 8);
            }

            // S^T = K Q^T: C rows = k-cols (quad*4+reg), C cols = q (lr).
            f32x4 s[4] = {};
            #pragma unroll
            for (int nt = 0; nt < 4; ++nt)
                #pragma unroll
                for (int kk = 0; kk < 2; ++kk) {
                    ushort8 bb = *(ushort8*)&Ks[buf][(nt * 2 + (lr >> 3)) * 512 +
                                                     (kk * 4 + quad) * 64 + (lr & 7) * 8];
                    s[nt] = MFMA16(bb, qf[kk], s[nt]);
                }
            // causal mask on RAW scores (diagonal tile only); scale folds later
            if (kt == qt) {
                #pragma unroll
                for (int nt = 0; nt < 4; ++nt)
                    #pragma unroll
                    for (int reg = 0; reg < 4; ++reg) {
                        int kc = nt * 16 + quad * 4 + reg;
                        if (kc > qrow) s[nt][reg] = -1e30f;
                    }
            }
            // row max: 15 in-lane + 2 shuffles (raw), one mult to scaled domain
            float mx = -1e30f;
            #pragma unroll
            for (int nt = 0; nt < 4; ++nt)
                #pragma unroll
                for (int reg = 0; reg < 4; ++reg) mx = fmaxf(mx, s[nt][reg]);
            mx = fmaxf(mx, __shfl_xor(mx, 16, 64));
            mx = fmaxf(mx, __shfl_xor(mx, 32, 64));
            float mxs = mx * kscale;
            // defer-max (T13): only rescale when the max actually moved
            if (!__all(mxs <= m_i + 8.0f)) {
                float mnew = fmaxf(m_i, mxs);
                float alpha = EXP2(m_i - mnew);
                m_i = mnew;
                l_i *= alpha;
                #pragma unroll
                for (int reg = 0; reg < 4; ++reg) {
                    float ar = __shfl(alpha, bsrc + reg, 64);  // alpha of row quad*4+reg
                    #pragma unroll
                    for (int dt = 0; dt < 4; ++dt) o_acc[dt][reg] *= ar;
                }
            }
            // P = exp2(s*kscale - m_i) via fmaf; sum
            float p4[4][4];
            float rs = 0.f;
            #pragma unroll
            for (int nt = 0; nt < 4; ++nt)
                #pragma unroll
                for (int reg = 0; reg < 4; ++reg) {
                    float pv = EXP2(fmaf(s[nt][reg], kscale, -m_i));
                    p4[nt][reg] = pv;
                    rs += pv;
                }
            rs += __shfl_xor(rs, 16, 64);
            rs += __shfl_xor(rs, 32, 64);
            l_i += rs;
            // P^T -> Ps: packed cvt, 4 f32 -> one b64 per nt (own rows only)
            #pragma unroll
            for (int nt = 0; nt < 4; ++nt) {
                unsigned lo = pk2(p4[nt][0], p4[nt][1]);
                unsigned hi = pk2(p4[nt][2], p4[nt][3]);
                unsigned long long pk = ((unsigned long long)hi << 32) | lo;
                *(unsigned long long*)&Ps[qrow * 72 + nt * 16 + quad * 4] = pk;
            }

            __syncthreads();  // barrier B: Ps ordered+visible; V(kt) drained

            // O += P V  (A = Ps rows, B = V^T rows; contiguous-k both sides)
            #pragma unroll
            for (int kk = 0; kk < 2; ++kk) {
                ushort8 pa = *(ushort8*)&Ps[(w * 16 + lr) * 72 + kk * 32 + quad * 8];
                #pragma unroll
                for (int dt = 0; dt < 4; ++dt) {
                    ushort8 vb = *(ushort8*)&Vts[(dt * 2 + (lr >> 3)) * 512 +
                                                 (kk * 4 + quad) * 64 + (lr & 7) * 8];
                    o_acc[dt] = MFMA16(pa, vb, o_acc[dt]);
                }
            }
        }

        // epilogue: normalize (l of row quad*4+reg via broadcast), write bf16
        float rinv = 1.0f / l_i;
        float rl[4];
        #pragma unroll
        for (int reg = 0; reg < 4; ++reg) rl[reg] = __shfl(rinv, bsrc + reg, 64);
        #pragma unroll
        for (int dt = 0; dt < 4; ++dt)
            #pragma unroll
            for (int reg = 0; reg < 4; ++reg) {
                int row = w * 16 + quad * 4 + reg;
                int tq = qt * 64 + row;
                o_ws[((size_t)(b * 2048 + tq) << 10) + h * 64 + dt * 16 + lr] =
                    f2bf(o_acc[dt][reg] * rl[reg]);
            }
    }
}

extern "C" void kernel_launch(void* const* d_in, const int* in_sizes, int n_in,
                              void* d_out, int out_size, void* d_ws, size_t ws_size,
                              hipStream_t stream)
{
    const float* x    = (const float*)d_in[0];
    const float* Wqkv = (const float*)d_in[1];
    const float* bqkv = (const float*)d_in[2];
    const float* Wout = (const float*)d_in[3];
    const float* bout = (const float*)d_in[4];
    float* out = (float*)d_out;

    u16* qkvb = (u16*)d_ws;                    // q | k | vT, 3 * 8388608 elems
    u16* xb   = qkvb + (size_t)3 * 8388608;    // 8388608 elems; reused as attn_o
    u16* wT   = qkvb + (size_t)4 * 8388608;    // up to 3072*1024 elems
    u16* attn_o = xb;

    convert_bf16<<<4096, 256, 0, stream>>>(x, xb);
    transpose_convert<<<dim3(16, 48), 256, 0, stream>>>(Wqkv, wT, 3072, 1024);
    qkv_gemm<<<dim3(32, 12), 512, 0, stream>>>(xb, wT, bqkv, qkvb);
    attn_kernel<<<dim3(16, 16, 4), 256, 0, stream>>>(qkvb, attn_o);
    transpose_convert<<<dim3(16, 16), 256, 0, stream>>>(Wout, wT, 1024, 1024);
    out_gemm<<<dim3(32, 8), 512, 0, stream>>>(attn_o, wT, bout, out);
}

// Round 12
// 268.166 us; speedup vs baseline: 1.0960x; 1.0156x over previous
//
#include <hip/hip_runtime.h>
#include <hip/hip_bf16.h>
#include <stdint.h>

typedef unsigned short u16;
typedef __bf16 bf16x8 __attribute__((ext_vector_type(8)));
typedef float f32x4 __attribute__((ext_vector_type(4)));
typedef u16 ushort8 __attribute__((ext_vector_type(8)));
typedef short short4v __attribute__((ext_vector_type(4)));

__device__ __forceinline__ u16 f2bf(float f) {
    unsigned int u = __builtin_bit_cast(unsigned int, f);
    u += 0x7fffu + ((u >> 16) & 1u);
    return (u16)(u >> 16);
}

// 2x f32 -> packed bf16 (RNE) via the HIP intrinsic (proven round 7).
__device__ __forceinline__ unsigned pk2(float a, float b) {
    __hip_bfloat162 h = __float22bfloat162_rn(float2{a, b});
    unsigned u;
    __builtin_memcpy(&u, &h, 4);
    return u;
}

#define MFMA16(a, b, c) __builtin_amdgcn_mfma_f32_16x16x32_bf16( \
    __builtin_bit_cast(bf16x8, a), __builtin_bit_cast(bf16x8, b), c, 0, 0, 0)

#if defined(__has_builtin)
#if __has_builtin(__builtin_amdgcn_exp2f)
#define EXP2(x) __builtin_amdgcn_exp2f(x)
#endif
#endif
#ifndef EXP2
#define EXP2(x) __expf((x) * 0.69314718f)
#endif

// async global->LDS, 16B per lane. LDS dest = wave-uniform base + lane*16.
__device__ __forceinline__ void async16(void* lds, const void* g) {
    __builtin_amdgcn_global_load_lds(
        (const __attribute__((address_space(1))) unsigned int*)(uintptr_t)g,
        (__attribute__((address_space(3))) unsigned int*)(unsigned int)(uintptr_t)lds,
        16, 0, 0);
}

// ---------------------------------------------------------------------------
// transpose+convert body: src fp32 [K][N] -> dst bf16 [N][K]; one 64x64 tile.
// T = 64x68 u16 scratch (caller-provided LDS). Block-uniform.
// ---------------------------------------------------------------------------
__device__ __forceinline__ void transpose_tile(
    const float* __restrict__ src, u16* __restrict__ dst,
    int N, int K, int k0, int n0, int tid, u16* T)
{
    const int rr = tid >> 4, cc = (tid & 15) * 4;
    #pragma unroll
    for (int rnd = 0; rnd < 4; ++rnd) {
        int r = rr + rnd * 16;
        float4 f = *(const float4*)&src[(size_t)(k0 + r) * N + n0 + cc];
        u16 v[4] = {f2bf(f.x), f2bf(f.y), f2bf(f.z), f2bf(f.w)};
        *(unsigned long long*)&T[r * 68 + cc] = *(unsigned long long*)v;
    }
    __syncthreads();
    #pragma unroll
    for (int rnd = 0; rnd < 4; ++rnd) {
        int rn = rr + rnd * 16;
        u16 v[4];
        #pragma unroll
        for (int j = 0; j < 4; ++j) v[j] = T[(cc + j) * 68 + rn];
        *(unsigned long long*)&dst[(size_t)(n0 + rn) * K + k0 + cc] =
            *(unsigned long long*)v;
    }
}

// ---------------------------------------------------------------------------
// prep: convert x fp32->bf16 (blocks 0..4095) UNION transpose Wqkv
// (blocks 4096..4863). Both must precede qkv_gemm; merged to save a launch.
// ---------------------------------------------------------------------------
__global__ __launch_bounds__(256) void prep_kernel(
    const float* __restrict__ x, u16* __restrict__ xb,
    const float* __restrict__ Wqkv, u16* __restrict__ wT)
{
    __shared__ u16 T[64 * 68];
    const int blk = blockIdx.x, tid = threadIdx.x;
    if (blk < 4096) {
        int i = blk * 256 + tid;
        float4 f0 = ((const float4*)x)[i * 2];
        float4 f1 = ((const float4*)x)[i * 2 + 1];
        ushort8 v;
        v[0]=f2bf(f0.x); v[1]=f2bf(f0.y); v[2]=f2bf(f0.z); v[3]=f2bf(f0.w);
        v[4]=f2bf(f1.x); v[5]=f2bf(f1.y); v[6]=f2bf(f1.z); v[7]=f2bf(f1.w);
        ((ushort8*)xb)[i] = v;
    } else {
        int idx = blk - 4096;                    // 0..767 = 16 x 48 tiles
        int k0 = (idx & 15) * 64, n0 = (idx >> 4) * 64;
        transpose_tile(Wqkv, wT, 3072, 1024, k0, n0, tid, T);
    }
}

// ===========================================================================
// qkv mainloop: 256x256 / BK=32, 512 threads = 8 waves (2M x 4N).
// 2 x 32KB LDS -> 2 blocks/CU. (round-4 version, PROVEN: ~83.5us)
// ===========================================================================
#define NT32 32      // K=1024 / BK=32
#define BUF32 16384  // u16 per buffer: A 8192 (256x32) + B 8192 (256x32)

__device__ __forceinline__ void stage32(
    const u16* __restrict__ A, const u16* __restrict__ Bt,
    u16* Lb, int m0, int n0, int k0, int w, int lane)
{
    const int rbl = lane >> 5;          // which rb of the wave's pair
    const int chunk = (lane >> 3) & 3;  // k-chunk of 8 u16
    const int row = lane & 7;
    #pragma unroll
    for (int r = 0; r < 2; ++r) {
        int rb = w * 4 + r * 2 + rbl;
        async16(Lb + (w * 4 + r * 2) * 256,
                A + (size_t)(m0 + rb * 8 + row) * 1024 + k0 + chunk * 8);
    }
    #pragma unroll
    for (int r = 0; r < 2; ++r) {
        int rb = w * 4 + r * 2 + rbl;
        async16(Lb + 8192 + (w * 4 + r * 2) * 256,
                Bt + (size_t)(n0 + rb * 8 + row) * 1024 + k0 + chunk * 8);
    }
}

__device__ __forceinline__ void gemm_mainloop32(
    const u16* __restrict__ A, const u16* __restrict__ Bt,
    u16* L, int m0, int n0, int tid, f32x4 acc[8][4])
{
    const int lane = tid & 63, w = tid >> 6;
    const int lr = lane & 15, quad = lane >> 4;
    const int wm = w >> 2, wn = w & 3;
    const int arb = wm * 16 + (lr >> 3);   // + mt*2
    const int brb = wn * 8 + (lr >> 3);    // + nt*2
    const int foff = quad * 64 + (lr & 7) * 8;

    // prologue: stage T0, drain, barrier
    stage32(A, Bt, L, m0, n0, 0, w, lane);
    asm volatile("s_waitcnt vmcnt(0)" ::: "memory");
    __builtin_amdgcn_s_barrier();
    asm volatile("" ::: "memory");

    #pragma unroll 2
    for (int t = 0; t < NT32; ++t) {
        const u16* As = L + (t & 1) * BUF32;
        const u16* Bs = As + 8192;

        // stage next tile; counted wait: tile t landed, t+1 stays in flight
        if (t + 1 < NT32) {
            stage32(A, Bt, L + ((t + 1) & 1) * BUF32, m0, n0, (t + 1) * 32,
                    w, lane);
            asm volatile("s_waitcnt vmcnt(4)" ::: "memory");
        } else {
            asm volatile("s_waitcnt vmcnt(0)" ::: "memory");
        }
        __builtin_amdgcn_s_barrier();   // open: buf[t&1] visible to all waves
        asm volatile("" ::: "memory");

        ushort8 b[4], a03[4], a47[4];
        #pragma unroll
        for (int nt = 0; nt < 4; ++nt)
            b[nt] = *(const ushort8*)&Bs[(brb + nt * 2) * 256 + foff];
        #pragma unroll
        for (int mt = 0; mt < 4; ++mt)
            a03[mt] = *(const ushort8*)&As[(arb + mt * 2) * 256 + foff];
        __builtin_amdgcn_sched_barrier(0);   // pin issue order: b+a03 first
        #pragma unroll
        for (int mt = 0; mt < 4; ++mt)
            a47[mt] = *(const ushort8*)&As[(arb + (mt + 4) * 2) * 256 + foff];
        // counted lgkm: 12 issued, wait to <=4 -> b+a03 (8 oldest) done;
        // a47 reads fly under the first MFMA cluster.
        asm volatile("s_waitcnt lgkmcnt(4)" ::: "memory");
        __builtin_amdgcn_sched_barrier(0);
        __builtin_amdgcn_s_setprio(1);
        #pragma unroll
        for (int mt = 0; mt < 4; ++mt)
            #pragma unroll
            for (int nt = 0; nt < 4; ++nt)
                acc[mt][nt] = MFMA16(a03[mt], b[nt], acc[mt][nt]);
        __builtin_amdgcn_s_setprio(0);
        asm volatile("s_waitcnt lgkmcnt(0)" ::: "memory");
        __builtin_amdgcn_sched_barrier(0);
        __builtin_amdgcn_s_setprio(1);
        #pragma unroll
        for (int mt = 0; mt < 4; ++mt)
            #pragma unroll
            for (int nt = 0; nt < 4; ++nt)
                acc[mt + 4][nt] = MFMA16(a47[mt], b[nt], acc[mt + 4][nt]);
        __builtin_amdgcn_s_setprio(0);
        __builtin_amdgcn_s_barrier();   // close: reads done before restage
        asm volatile("" ::: "memory");
    }
}

// ---------------------------------------------------------------------------
// Kernel: qkv = xb @ WqkvT^T + bqkv
// q,k stored [b,h,t,64]; v stored TRANSPOSED [b,h,64,t]
// grid (32, 12), block 512.
// ---------------------------------------------------------------------------
__global__ __launch_bounds__(512, 2) void qkv_gemm(
    const u16* __restrict__ xb, const u16* __restrict__ Wt,
    const float* __restrict__ bias, u16* __restrict__ qkvb)
{
    __shared__ u16 L[2 * BUF32];   // 64 KB -> 2 blocks/CU
    const int m0 = blockIdx.x * 256, n0 = blockIdx.y * 256;
    const int tid = threadIdx.x;
    f32x4 acc[8][4] = {};
    gemm_mainloop32(xb, Wt, L, m0, n0, tid, acc);

    const int lane = tid & 63, w = tid >> 6;
    const int lr = lane & 15, quad = lane >> 4;
    const int wm = w >> 2, wn = w & 3;
    const int which = n0 >> 10;  // uniform per block (256 divides 1024)
    float bv[4];
    #pragma unroll
    for (int nt = 0; nt < 4; ++nt) bv[nt] = bias[n0 + wn * 64 + nt * 16 + lr];

    if (which == 2) {
        // V: transposed store [b,h,d,t], 4 regs = 4 consecutive t -> b64
        u16* vT = qkvb + (size_t)2 * 8388608;
        #pragma unroll
        for (int nt = 0; nt < 4; ++nt) {
            int n = n0 + wn * 64 + nt * 16 + lr;
            int hh = (n >> 6) & 15, d = n & 63;
            #pragma unroll
            for (int mt = 0; mt < 8; ++mt) {
                int mbase = m0 + wm * 128 + mt * 16 + quad * 4;
                int b_idx = mbase >> 11, t0 = mbase & 2047;
                short4v o4;
                #pragma unroll
                for (int reg = 0; reg < 4; ++reg)
                    o4[reg] = (short)f2bf(acc[mt][nt][reg] + bv[nt]);
                *(short4v*)&vT[((size_t)(b_idx * 16 + hh) * 64 + d) * 2048 + t0] = o4;
            }
        }
    } else {
        u16* dst = qkvb + (size_t)which * 8388608;
        #pragma unroll
        for (int mt = 0; mt < 8; ++mt)
          #pragma unroll
          for (int nt = 0; nt < 4; ++nt) {
            int n = n0 + wn * 64 + nt * 16 + lr;
            int hh = (n >> 6) & 15, d = n & 63;
            #pragma unroll
            for (int reg = 0; reg < 4; ++reg) {
                int m = m0 + wm * 128 + mt * 16 + quad * 4 + reg;
                int b_idx = m >> 11, t_idx = m & 2047;
                dst[(((size_t)(b_idx * 16 + hh) * 2048 + t_idx) << 6) + d] =
                    f2bf(acc[mt][nt][reg] + bv[nt]);
            }
          }
    }
}

// ===========================================================================
// out_gemm mainloop (round-1 PROVEN): 256x128 / BK=64, 8 waves (4M x 2N),
// 3-buffer LDS ring, counted vmcnt(12)/(6)/(0). Grid 32x8 = 256. Unchanged.
// ===========================================================================
#define KT16 16  // K=1024 / BK=64

__device__ __forceinline__ void stage_tile256(
    const u16* __restrict__ A, const u16* __restrict__ Bt,
    u16* Lb, int m0, int n0, int k0, int w, int grow, int gchunk)
{
    #pragma unroll
    for (int r = 0; r < 4; ++r) {
        int rb = w * 4 + r;   // 32 rowblocks of A
        async16(Lb + rb * 512,
                A + (size_t)(m0 + rb * 8 + grow) * 1024 + k0 + gchunk * 8);
    }
    #pragma unroll
    for (int r = 0; r < 2; ++r) {
        int rb = w * 2 + r;   // 16 rowblocks of B
        async16(Lb + 16384 + rb * 512,
                Bt + (size_t)(n0 + rb * 8 + grow) * 1024 + k0 + gchunk * 8);
    }
}

__device__ __forceinline__ void gemm_mainloop256(
    const u16* __restrict__ A, const u16* __restrict__ Bt,
    u16* L, int m0, int n0, int tid, f32x4 acc[4][4])
{
    const int lane = tid & 63, w = tid >> 6;
    const int lr = lane & 15, quad = lane >> 4;
    const int wm = w >> 1, wn = w & 1;
    const int grow = lane & 7, gchunk = lane >> 3;

    // prologue: stage T0, T1
    stage_tile256(A, Bt, L,         m0, n0, 0,  w, grow, gchunk);
    stage_tile256(A, Bt, L + 24576, m0, n0, 64, w, grow, gchunk);

    u16* Lc = L;              // compute buffer (tile t)
    u16* Ls = L + 49152;      // stage buffer (tile t+2)
    u16* const Lend = L + 73728;

    for (int t = 0; t < KT16; ++t) {
        if (t < KT16 - 2)
            stage_tile256(A, Bt, Ls, m0, n0, (t + 2) * 64, w, grow, gchunk);

        if (t < KT16 - 2)       asm volatile("s_waitcnt vmcnt(12)" ::: "memory");
        else if (t == KT16 - 2) asm volatile("s_waitcnt vmcnt(6)"  ::: "memory");
        else                    asm volatile("s_waitcnt vmcnt(0)"  ::: "memory");
        __builtin_amdgcn_s_barrier();
        asm volatile("" ::: "memory");

        const u16* As = Lc;
        const u16* Bs = Lc + 16384;
        __builtin_amdgcn_s_setprio(1);
        #pragma unroll
        for (int kk = 0; kk < 2; ++kk) {
            ushort8 a[4], b[4];
            #pragma unroll
            for (int mt = 0; mt < 4; ++mt) {
                int rb = wm * 8 + mt * 2 + (lr >> 3);
                a[mt] = *(const ushort8*)&As[rb * 512 + (kk * 4 + quad) * 64 + (lr & 7) * 8];
            }
            #pragma unroll
            for (int nt = 0; nt < 4; ++nt) {
                int rb = wn * 8 + nt * 2 + (lr >> 3);
                b[nt] = *(const ushort8*)&Bs[rb * 512 + (kk * 4 + quad) * 64 + (lr & 7) * 8];
            }
            #pragma unroll
            for (int mt = 0; mt < 4; ++mt)
                #pragma unroll
                for (int nt = 0; nt < 4; ++nt)
                    acc[mt][nt] = MFMA16(a[mt], b[nt], acc[mt][nt]);
        }
        __builtin_amdgcn_s_setprio(0);
        asm volatile("" ::: "memory");
        __builtin_amdgcn_s_barrier();
        asm volatile("" ::: "memory");

        Lc += 24576; if (Lc == Lend) Lc = L;
        Ls += 24576; if (Ls == Lend) Ls = L;
    }
}

// ---------------------------------------------------------------------------
// Kernel: out = attn_o @ WoutT^T + bout (fp32 out)
// grid (32, 8), block 512.
// ---------------------------------------------------------------------------
__global__ __launch_bounds__(512, 2) void out_gemm(
    const u16* __restrict__ A, const u16* __restrict__ Wt,
    const float* __restrict__ bias, float* __restrict__ out)
{
    __shared__ u16 L[73728];
    const int m0 = blockIdx.x * 256, n0 = blockIdx.y * 128;
    const int tid = threadIdx.x;
    f32x4 acc[4][4] = {};
    gemm_mainloop256(A, Wt, L, m0, n0, tid, acc);

    const int lane = tid & 63, w = tid >> 6;
    const int lr = lane & 15, quad = lane >> 4;
    const int wm = w >> 1, wn = w & 1;
    float bv[4];
    #pragma unroll
    for (int nt = 0; nt < 4; ++nt) bv[nt] = bias[n0 + wn * 64 + nt * 16 + lr];
    #pragma unroll
    for (int mt = 0; mt < 4; ++mt)
      #pragma unroll
      for (int nt = 0; nt < 4; ++nt)
        #pragma unroll
        for (int reg = 0; reg < 4; ++reg) {
            int m = m0 + wm * 64 + mt * 16 + quad * 4 + reg;
            int n = n0 + wn * 64 + nt * 16 + lr;
            out[(size_t)m * 1024 + n] = acc[mt][nt][reg] + bv[nt];
        }
}

// ---------------------------------------------------------------------------
// Flash attention — round-7 PROVEN body (272.3us build), with the Wout
// transpose MERGED as grid slice blockIdx.z==4 (256 blocks): wT is free
// during attn (qkv done reading WqkvT; out_gemm reads WoutT after), exactly
// the window the previous separate launch used. Saves one launch (~9us).
// Shared memory is a union block: attn carve = Ks(8192)|Vts(4096)|Ps(4608)
// u16 = 33792 B (unchanged); transpose uses the first 4352 u16.
// ---------------------------------------------------------------------------
__global__ __launch_bounds__(256) void attn_kernel(
    const u16* __restrict__ qkvb, u16* __restrict__ o_ws,
    const float* __restrict__ Wout, u16* __restrict__ wT)
{
    __shared__ u16 SH[16896];
    const int tid = threadIdx.x;

    if (blockIdx.z == 4) {   // Wout transpose slice (16x16 tiles of 64x64)
        int idx = blockIdx.x + 16 * blockIdx.y;   // 0..255
        int k0 = (idx & 15) * 64, n0 = (idx >> 4) * 64;
        transpose_tile(Wout, wT, 1024, 1024, k0, n0, tid, SH);
        return;
    }

    u16* Ks0 = SH;            // Ks[2][4096]
    u16* Vts = SH + 8192;     // [4096]
    u16* Ps  = SH + 12288;    // [64*72]

    const int orig = blockIdx.x + 16 * (blockIdx.y + 16 * blockIdx.z);  // 0..1023
    const int work = (orig & 7) * 128 + (orig >> 3);   // bijective (1024 % 8 == 0)
    const int p = work & 15, h = (work >> 4) & 15, b = work >> 8;
    const size_t bh = (size_t)(b * 16 + h) * 131072;
    const u16* Qb = qkvb + bh;
    const u16* Kb = qkvb + 8388608 + bh;
    const u16* Vt = qkvb + 2 * 8388608 + bh;   // [64][2048]
    const int lane = tid & 63, w = tid >> 6;
    const int lr = lane & 15, quad = lane >> 4;
    const int grow = lane & 7, gchunk = lane >> 3;
    const float kscale = 0.125f * 1.44269504f;  // scale * log2(e)

    for (int pass = 0; pass < 2; ++pass) {
        const int qt = pass ? (31 - p) : p;
        // Q A-fragments straight from global (contiguous k-chunks)
        ushort8 qf[2];
        {
            const u16* qr = Qb + (size_t)(qt * 64 + w * 16 + lr) * 64 + quad * 8;
            qf[0] = *(const ushort8*)qr;
            qf[1] = *(const ushort8*)(qr + 32);
        }
        f32x4 o_acc[4] = {};
        float m_i = -1e30f, l_i = 0.f;       // lane-local (scaled domain)
        const int qrow = w * 16 + lr;        // in-tile q row this lane reduces
        const int bsrc = (lane & 48) + ((lane >> 4) << 2);  // quad*16 + quad*4

        __syncthreads();  // prev pass's LDS reads done
        #pragma unroll
        for (int r = 0; r < 2; ++r) {   // stage K(0)
            int rb = w * 2 + r;
            async16(&Ks0[rb * 512], Kb + (size_t)(rb * 8 + grow) * 64 + gchunk * 8);
        }

        for (int kt = 0; kt <= qt; ++kt) {
            const int buf = kt & 1;
            __syncthreads();  // barrier A: K(kt) staged; prev iter's PV reads done

            // prefetch K(kt+1) into other buffer; stage V(kt) just-in-time
            #pragma unroll
            for (int r = 0; r < 2; ++r) {
                int rb = w * 2 + r;
                if (kt < qt)
                    async16(&Ks0[(buf ^ 1) * 4096 + rb * 512],
                            Kb + (size_t)((kt + 1) * 64 + rb * 8 + grow) * 64 + gchunk * 8);
                async16(&Vts[rb * 512],
                        Vt + (size_t)(rb * 8 + grow) * 2048 + kt * 64 + gchunk * 8);
            }

            // S^T = K Q^T: C rows = k-cols (quad*4+reg), C cols = q (lr).
            f32x4 s[4] = {};
            #pragma unroll
            for (int nt = 0; nt < 4; ++nt)
                #pragma unroll
                for (int kk = 0; kk < 2; ++kk) {
                    ushort8 bb = *(ushort8*)&Ks0[buf * 4096 +
                                                 (nt * 2 + (lr >> 3)) * 512 +
                                                 (kk * 4 + quad) * 64 + (lr & 7) * 8];
                    s[nt] = MFMA16(bb, qf[kk], s[nt]);
                }
            // causal mask on RAW scores (diagonal tile only); scale folds later
            if (kt == qt) {
                #pragma unroll
                for (int nt = 0; nt < 4; ++nt)
                    #pragma unroll
                    for (int reg = 0; reg < 4; ++reg) {
                        int kc = nt * 16 + quad * 4 + reg;
                        if (kc > qrow) s[nt][reg] = -1e30f;
                    }
            }
            // row max: 15 in-lane + 2 shuffles (raw), one mult to scaled domain
            float mx = -1e30f;
            #pragma unroll
            for (int nt = 0; nt < 4; ++nt)
                #pragma unroll
                for (int reg = 0; reg < 4; ++reg) mx = fmaxf(mx, s[nt][reg]);
            mx = fmaxf(mx, __shfl_xor(mx, 16, 64));
            mx = fmaxf(mx, __shfl_xor(mx, 32, 64));
            float mxs = mx * kscale;
            // defer-max (T13): only rescale when the max actually moved
            if (!__all(mxs <= m_i + 8.0f)) {
                float mnew = fmaxf(m_i, mxs);
                float alpha = EXP2(m_i - mnew);
                m_i = mnew;
                l_i *= alpha;
                #pragma unroll
                for (int reg = 0; reg < 4; ++reg) {
                    float ar = __shfl(alpha, bsrc + reg, 64);  // alpha of row quad*4+reg
                    #pragma unroll
                    for (int dt = 0; dt < 4; ++dt) o_acc[dt][reg] *= ar;
                }
            }
            // P = exp2(s*kscale - m_i) via fmaf; sum
            float p4[4][4];
            float rs = 0.f;
            #pragma unroll
            for (int nt = 0; nt < 4; ++nt)
                #pragma unroll
                for (int reg = 0; reg < 4; ++reg) {
                    float pv = EXP2(fmaf(s[nt][reg], kscale, -m_i));
                    p4[nt][reg] = pv;
                    rs += pv;
                }
            rs += __shfl_xor(rs, 16, 64);
            rs += __shfl_xor(rs, 32, 64);
            l_i += rs;
            // P^T -> Ps: packed cvt, 4 f32 -> one b64 per nt (own rows only)
            #pragma unroll
            for (int nt = 0; nt < 4; ++nt) {
                unsigned lo = pk2(p4[nt][0], p4[nt][1]);
                unsigned hi = pk2(p4[nt][2], p4[nt][3]);
                unsigned long long pk = ((unsigned long long)hi << 32) | lo;
                *(unsigned long long*)&Ps[qrow * 72 + nt * 16 + quad * 4] = pk;
            }

            __syncthreads();  // barrier B: Ps ordered+visible; V(kt) drained

            // O += P V  (A = Ps rows, B = V^T rows; contiguous-k both sides)
            #pragma unroll
            for (int kk = 0; kk < 2; ++kk) {
                ushort8 pa = *(ushort8*)&Ps[(w * 16 + lr) * 72 + kk * 32 + quad * 8];
                #pragma unroll
                for (int dt = 0; dt < 4; ++dt) {
                    ushort8 vb = *(ushort8*)&Vts[(dt * 2 + (lr >> 3)) * 512 +
                                                 (kk * 4 + quad) * 64 + (lr & 7) * 8];
                    o_acc[dt] = MFMA16(pa, vb, o_acc[dt]);
                }
            }
        }

        // epilogue: normalize (l of row quad*4+reg via broadcast), write bf16
        float rinv = 1.0f / l_i;
        float rl[4];
        #pragma unroll
        for (int reg = 0; reg < 4; ++reg) rl[reg] = __shfl(rinv, bsrc + reg, 64);
        #pragma unroll
        for (int dt = 0; dt < 4; ++dt)
            #pragma unroll
            for (int reg = 0; reg < 4; ++reg) {
                int row = w * 16 + quad * 4 + reg;
                int tq = qt * 64 + row;
                o_ws[((size_t)(b * 2048 + tq) << 10) + h * 64 + dt * 16 + lr] =
                    f2bf(o_acc[dt][reg] * rl[reg]);
            }
    }
}

extern "C" void kernel_launch(void* const* d_in, const int* in_sizes, int n_in,
                              void* d_out, int out_size, void* d_ws, size_t ws_size,
                              hipStream_t stream)
{
    const float* x    = (const float*)d_in[0];
    const float* Wqkv = (const float*)d_in[1];
    const float* bqkv = (const float*)d_in[2];
    const float* Wout = (const float*)d_in[3];
    const float* bout = (const float*)d_in[4];
    float* out = (float*)d_out;

    u16* qkvb = (u16*)d_ws;                    // q | k | vT, 3 * 8388608 elems
    u16* xb   = qkvb + (size_t)3 * 8388608;    // 8388608 elems; reused as attn_o
    u16* wT   = qkvb + (size_t)4 * 8388608;    // up to 3072*1024 elems
    u16* attn_o = xb;

    prep_kernel<<<4864, 256, 0, stream>>>(x, xb, Wqkv, wT);
    qkv_gemm<<<dim3(32, 12), 512, 0, stream>>>(xb, wT, bqkv, qkvb);
    attn_kernel<<<dim3(16, 16, 5), 256, 0, stream>>>(qkvb, attn_o, Wout, wT);
    out_gemm<<<dim3(32, 8), 512, 0, stream>>>(attn_o, wT, bout, out);
}